// Round 6
// baseline (322.327 us; speedup 1.0000x reference)
//
#include <hip/hip_runtime.h>
#include <cstdint>
#include <cmath>

#define NROWS 8192
#define KDIM  512            // elements; also bytes/row in fp8
#define NBLK  8192           // gemm grid size (128 x 64)

typedef int    i32x8  __attribute__((ext_vector_type(8)));
typedef float  f32x16 __attribute__((ext_vector_type(16)));
typedef unsigned char u8;

// --- Kernel 1: row L2-normalize fp32 -> fp8 e4m3, written in FRAGMENT-MAJOR
// packed layout so the GEMM reads MFMA operands directly from global, coalesced:
//   row r (0..16383), element k (0..511):
//   tile t=r>>5, rr=r&31, kb=k>>6, q=(k&63)>>5, b=k&31
//   P[t*16384 + kb*2048 + (q*32+rr)*32 + b]
// Then GEMM lane (row rr=lane&31, k-half q=lane>>5) of frag (t,kb) reads its
// 32 operand bytes at P + t*16384 + kb*2048 + lane*32 — one aligned 32B load.
// One wave per row; lane l holds elements [8l, 8l+8). Also zeroes acc + ticket.
__global__ __launch_bounds__(256) void nrm_kernel(const float* __restrict__ zi,
                                                  const float* __restrict__ zj,
                                                  u8* __restrict__ out,
                                                  double* __restrict__ acc,
                                                  unsigned* __restrict__ cnt) {
    if (blockIdx.x == 0 && threadIdx.x == 0) { acc[0] = 0.0; acc[1] = 0.0; cnt[0] = 0u; }
    const int wave = threadIdx.x >> 6;
    const int lane = threadIdx.x & 63;
    const int row  = blockIdx.x * 4 + wave;            // 0..16383
    const float* src = (row < NROWS) ? zi + (size_t)row * KDIM
                                     : zj + (size_t)(row - NROWS) * KDIM;
    float4 a = ((const float4*)src)[2 * lane];      // elements 8l..8l+3
    float4 b = ((const float4*)src)[2 * lane + 1];  // elements 8l+4..8l+7
    float ss = a.x*a.x + a.y*a.y + a.z*a.z + a.w*a.w
             + b.x*b.x + b.y*b.y + b.z*b.z + b.w*b.w;
    #pragma unroll
    for (int off = 32; off >= 1; off >>= 1) ss += __shfl_xor(ss, off, 64);
    const float inv = 1.0f / fmaxf(sqrtf(ss), 1e-12f);
    int p0 = 0, p1 = 0;
    p0 = __builtin_amdgcn_cvt_pk_fp8_f32(a.x * inv, a.y * inv, p0, false); // bytes 0,1
    p0 = __builtin_amdgcn_cvt_pk_fp8_f32(a.z * inv, a.w * inv, p0, true);  // bytes 2,3
    p1 = __builtin_amdgcn_cvt_pk_fp8_f32(b.x * inv, b.y * inv, p1, false);
    p1 = __builtin_amdgcn_cvt_pk_fp8_f32(b.z * inv, b.w * inv, p1, true);
    const int t  = row >> 5, rr = row & 31;
    const int kb = lane >> 3;              // k-block (64 B)
    const int q  = (lane & 7) >> 2;        // k-half within block
    const int b8 = (lane & 3) * 8;         // byte offset within 32B lane-row
    uint2 v; v.x = (unsigned)p0; v.y = (unsigned)p1;
    *(uint2*)(out + (size_t)t * 16384 + kb * 2048 + (q * 32 + rr) * 32 + b8) = v;
}

// --- Kernel 2: fused MX-fp8 A*B^T -> exp(10*dot) -> global sum -> (last block) loss.
// Block 128x128, 4 waves 2x2, wave tile 64x64 = 2x2 frags of 32x32x64 (R2 geometry —
// the occupancy sweet spot). NO LDS, NO __syncthreads in the K-loop: operands are
// loaded straight from the packed-fragment global buffer (L1/L2-resident, 8 MB)
// into registers, double-buffered, so the compiler emits fine-grained vmcnt
// (no barrier -> no vmcnt(0) drain — the R2-R4 structures' ~40% dead time).
// Pos-region diagonal skipped, added exactly at finalize.
__global__ __launch_bounds__(256) void gemm_exp_reduce(const u8* __restrict__ P,
                                                       double* __restrict__ acc,
                                                       unsigned* __restrict__ cnt,
                                                       float* __restrict__ out) {
    __shared__ float red[4];

    const int tid  = threadIdx.x;
    const int lane = tid & 63;
    const int wave = tid >> 6;
    const int mt0  = blockIdx.y * 4 + (wave >> 1) * 2;   // A 32-row tile indices
    const int nt0  = blockIdx.x * 4 + (wave & 1) * 2;    // B 32-row tile indices

    f32x16 accf[2][2];
    #pragma unroll
    for (int i = 0; i < 2; ++i)
        #pragma unroll
        for (int j = 0; j < 2; ++j)
            #pragma unroll
            for (int r = 0; r < 16; ++r)
                accf[i][j][r] = 0.f;

    const u8* pa0 = P + (size_t)mt0 * 16384 + lane * 32;
    const u8* pa1 = pa0 + 16384;
    const u8* pb0 = P + (size_t)nt0 * 16384 + lane * 32;
    const u8* pb1 = pb0 + 16384;

    i32x8 a0[2], b0[2], a1[2], b1[2];
    // prologue: kb=0 into buf0
    a0[0] = *(const i32x8*)(pa0);
    a0[1] = *(const i32x8*)(pa1);
    b0[0] = *(const i32x8*)(pb0);
    b0[1] = *(const i32x8*)(pb1);

    #pragma unroll
    for (int kk = 0; kk < 8; kk += 2) {
        {   // load kb=kk+1 into buf1 (always valid: kk+1 <= 7)
            const size_t o = (size_t)(kk + 1) * 2048;
            a1[0] = *(const i32x8*)(pa0 + o);
            a1[1] = *(const i32x8*)(pa1 + o);
            b1[0] = *(const i32x8*)(pb0 + o);
            b1[1] = *(const i32x8*)(pb1 + o);
        }
        #pragma unroll
        for (int mi = 0; mi < 2; ++mi)
            #pragma unroll
            for (int ni = 0; ni < 2; ++ni)
                accf[mi][ni] = __builtin_amdgcn_mfma_scale_f32_32x32x64_f8f6f4(
                    a0[mi], b0[ni], accf[mi][ni],
                    0, 0, 0, 0x7f7f7f7f, 0, 0x7f7f7f7f);
        if (kk + 2 < 8) {   // load kb=kk+2 into buf0
            const size_t o = (size_t)(kk + 2) * 2048;
            a0[0] = *(const i32x8*)(pa0 + o);
            a0[1] = *(const i32x8*)(pa1 + o);
            b0[0] = *(const i32x8*)(pb0 + o);
            b0[1] = *(const i32x8*)(pb1 + o);
        }
        #pragma unroll
        for (int mi = 0; mi < 2; ++mi)
            #pragma unroll
            for (int ni = 0; ni < 2; ++ni)
                accf[mi][ni] = __builtin_amdgcn_mfma_scale_f32_32x32x64_f8f6f4(
                    a1[mi], b1[ni], accf[mi][ni],
                    0, 0, 0, 0x7f7f7f7f, 0, 0x7f7f7f7f);
    }

    // epilogue: exp(10*d) = exp2(d*10/ln2); skip pos diagonal (bx==by tiles only)
    const float LOG2E10 = 14.4269504088896341f;
    float part = 0.f;
    const bool diagblk = (blockIdx.x == blockIdx.y);   // bx<64 => pos region
    if (diagblk) {
        #pragma unroll
        for (int mi = 0; mi < 2; ++mi)
            #pragma unroll
            for (int ni = 0; ni < 2; ++ni)
                #pragma unroll
                for (int r = 0; r < 16; ++r) {
                    // C/D 32x32: col=lane&31, row=(r&3)+8*(r>>2)+4*(lane>>5)
                    int rr = (mt0 + mi) * 32 + ((r & 3) + 8 * (r >> 2) + 4 * (lane >> 5));
                    int cc = (nt0 + ni) * 32 + (lane & 31);
                    if (rr != cc) part += exp2f(accf[mi][ni][r] * LOG2E10);
                }
    } else {
        #pragma unroll
        for (int mi = 0; mi < 2; ++mi)
            #pragma unroll
            for (int ni = 0; ni < 2; ++ni)
                #pragma unroll
                for (int r = 0; r < 16; ++r)
                    part += exp2f(accf[mi][ni][r] * LOG2E10);
    }

    #pragma unroll
    for (int off = 32; off >= 1; off >>= 1) part += __shfl_xor(part, off, 64);
    if (lane == 0) red[wave] = part;
    __syncthreads();
    if (tid == 0) {
        double s = (double)red[0] + (double)red[1] + (double)red[2] + (double)red[3];
        atomicAdd(&acc[(blockIdx.x < 64) ? 0 : 1], s);   // n-tile in zi region -> pos
        __threadfence();
        unsigned t = atomicAdd(cnt, 1u);
        if (t == NBLK - 1) {   // last block finalizes: loss = log1p(neg/pos)
            double pos = __hip_atomic_load(&acc[0], __ATOMIC_RELAXED,
                                           __HIP_MEMORY_SCOPE_AGENT) + 8192.0 * exp(10.0);
            double neg = __hip_atomic_load(&acc[1], __ATOMIC_RELAXED,
                                           __HIP_MEMORY_SCOPE_AGENT);
            out[0] = (float)log1p(neg / pos);
        }
    }
}

extern "C" void kernel_launch(void* const* d_in, const int* in_sizes, int n_in,
                              void* d_out, int out_size, void* d_ws, size_t ws_size,
                              hipStream_t stream) {
    const float* zi = (const float*)d_in[0];
    const float* zj = (const float*)d_in[1];
    u8* nrm = (u8*)d_ws;                                      // packed fp8, 8 MB
    double* acc = (double*)((char*)d_ws + (size_t)16384 * 512);
    unsigned* cnt = (unsigned*)(acc + 2);

    nrm_kernel<<<4096, 256, 0, stream>>>(zi, zj, nrm, acc, cnt);
    dim3 grid(128, 64);   // x: 16384/128 n-tiles, y: 8192/128 m-tiles
    gemm_exp_reduce<<<grid, 256, 0, stream>>>(nrm, acc, cnt, (float*)d_out);
}

// Round 7
// 267.689 us; speedup vs baseline: 1.2041x; 1.2041x over previous
//
#include <hip/hip_runtime.h>
#include <cstdint>
#include <cmath>

#define NROWS 8192
#define KDIM  512            // elements; also bytes/row in fp8
#define NPART 6176           // participating gemm blocks: 8192 - 2016 skipped lower-tri pos

typedef int    i32x4  __attribute__((ext_vector_type(4)));
typedef int    i32x8  __attribute__((ext_vector_type(8)));
typedef float  f32x16 __attribute__((ext_vector_type(16)));
typedef unsigned char u8;

#define AS1(p) ((const __attribute__((address_space(1))) void*)(p))
#define AS3(p) ((__attribute__((address_space(3))) void*)(p))

// --- Kernel 1: row L2-normalize fp32 -> fp8 e4m3 (OCP, HW cvt), one wave/row.
// zi rows [0,8192), zj rows [8192,16384). Also zeroes accumulators + ticket.
__global__ __launch_bounds__(256) void nrm_kernel(const float* __restrict__ zi,
                                                  const float* __restrict__ zj,
                                                  u8* __restrict__ out,
                                                  double* __restrict__ acc,
                                                  unsigned* __restrict__ cnt) {
    if (blockIdx.x == 0 && threadIdx.x == 0) { acc[0] = 0.0; acc[1] = 0.0; cnt[0] = 0u; }
    const int wave = threadIdx.x >> 6;
    const int lane = threadIdx.x & 63;
    const int row  = blockIdx.x * 4 + wave;            // 0..16383
    const float* src = (row < NROWS) ? zi + (size_t)row * KDIM
                                     : zj + (size_t)(row - NROWS) * KDIM;
    float4 a = ((const float4*)src)[lane];
    float4 b = ((const float4*)src)[lane + 64];
    float ss = a.x*a.x + a.y*a.y + a.z*a.z + a.w*a.w
             + b.x*b.x + b.y*b.y + b.z*b.z + b.w*b.w;
    #pragma unroll
    for (int off = 32; off >= 1; off >>= 1) ss += __shfl_xor(ss, off, 64);
    const float inv = 1.0f / fmaxf(sqrtf(ss), 1e-12f);
    int p0 = 0, p1 = 0;
    p0 = __builtin_amdgcn_cvt_pk_fp8_f32(a.x * inv, a.y * inv, p0, false);
    p0 = __builtin_amdgcn_cvt_pk_fp8_f32(a.z * inv, a.w * inv, p0, true);
    p1 = __builtin_amdgcn_cvt_pk_fp8_f32(b.x * inv, b.y * inv, p1, false);
    p1 = __builtin_amdgcn_cvt_pk_fp8_f32(b.z * inv, b.w * inv, p1, true);
    int* dst = (int*)(out + (size_t)row * KDIM);
    dst[lane]      = p0;
    dst[lane + 64] = p1;
}

// --- Kernel 2: fused MX-fp8 A*B^T -> exp(10*dot) -> global sum -> (last block) loss.
// R3's proven structure (113 µs, best of R2-R5): 128x128 block, 4 waves 2x2, wave
// tile 64x64 = 2x2 frags of 32x32x64, LDS XOR-swizzle, 2-barrier K-loop.
// NEW (R6): pos matrix zi*zi^T is SYMMETRIC -> lower-triangle pos blocks (bx<by)
// exit immediately; bx>by blocks count with weight 2 (exact: transposed block has
// identical MFMA values). 24.6% of GEMM work eliminated.
// Pos-region diagonal skipped, added exactly at finalize.
__global__ __launch_bounds__(256) void gemm_exp_reduce(const u8* __restrict__ A,
                                                       const u8* __restrict__ B,
                                                       double* __restrict__ acc,
                                                       unsigned* __restrict__ cnt,
                                                       float* __restrict__ out) {
    const int bx = blockIdx.x, by = blockIdx.y;
    const bool pos = (bx < 64);
    if (pos && bx < by) return;   // lower-triangle pos block: transpose of (by,bx)

    __shared__ u8 lA[128 * 64];   // 8 KB = 4 operand-tile regions of 2048 B
    __shared__ u8 lB[128 * 64];   // 8 KB
    __shared__ float red[4];

    const int tid  = threadIdx.x;
    const int lane = tid & 63;
    const int wave = tid >> 6;
    const int m0   = by * 128;
    const int n0   = bx * 128;
    const int wm   = (wave >> 1) * 64;
    const int wn   = (wave & 1) * 64;

    f32x16 accf[2][2];
    #pragma unroll
    for (int i = 0; i < 2; ++i)
        #pragma unroll
        for (int j = 0; j < 2; ++j)
            #pragma unroll
            for (int r = 0; r < 16; ++r)
                accf[i][j][r] = 0.f;

    // staging (verified R2/R3): wave w stages rows w*32..+31 into region w*2048;
    // instr c writes LDS [w*2048 + c*1024 + lane*16]; lane's global source is
    // row = w*32 + c*16 + (lane>>2), 16B-chunk b = (lane&3) ^ ((lane>>3)&3).
    const int bsw = (lane & 3) ^ ((lane >> 3) & 3);
    const u8* gA0 = A + (size_t)(m0 + wave * 32 + (lane >> 2)) * KDIM + bsw * 16;
    const u8* gB0 = B + (size_t)(n0 + wave * 32 + (lane >> 2)) * KDIM + bsw * 16;
    u8* lAd = &lA[wave * 2048 + lane * 16];
    u8* lBd = &lB[wave * 2048 + lane * 16];

    // fragment read: lane holds row r=lane&31, k-half q=lane>>5 (chunks 2q,2q+1);
    // swizzled chunk position p = r*4 + ((2q) ^ ((r>>1)&3))
    const int r_  = lane & 31;
    const int q_  = lane >> 5;
    const int p16 = (r_ * 4 + ((2 * q_) ^ ((r_ >> 1) & 3))) * 16;
    const int aT0 = (wave >> 1) * 2;
    const int bT0 = (wave & 1) * 2;

    for (int k0 = 0; k0 < KDIM; k0 += 64) {
        __syncthreads();
        #pragma unroll
        for (int c = 0; c < 2; ++c) {
            __builtin_amdgcn_global_load_lds(AS1(gA0 + k0 + (size_t)c * 16 * KDIM),
                                             AS3(lAd + c * 1024), 16, 0, 0);
            __builtin_amdgcn_global_load_lds(AS1(gB0 + k0 + (size_t)c * 16 * KDIM),
                                             AS3(lBd + c * 1024), 16, 0, 0);
        }
        __syncthreads();

        i32x8 af[2], bfr[2];
        #pragma unroll
        for (int mi = 0; mi < 2; ++mi) {
            const int off = (aT0 + mi) * 2048 + p16;
            i32x4 lo = *(const i32x4*)&lA[off];
            i32x4 hi = *(const i32x4*)&lA[off ^ 16];
            af[mi] = (i32x8){lo[0], lo[1], lo[2], lo[3], hi[0], hi[1], hi[2], hi[3]};
        }
        #pragma unroll
        for (int ni = 0; ni < 2; ++ni) {
            const int off = (bT0 + ni) * 2048 + p16;
            i32x4 lo = *(const i32x4*)&lB[off];
            i32x4 hi = *(const i32x4*)&lB[off ^ 16];
            bfr[ni] = (i32x8){lo[0], lo[1], lo[2], lo[3], hi[0], hi[1], hi[2], hi[3]};
        }
        #pragma unroll
        for (int mi = 0; mi < 2; ++mi)
            #pragma unroll
            for (int ni = 0; ni < 2; ++ni)
                accf[mi][ni] = __builtin_amdgcn_mfma_scale_f32_32x32x64_f8f6f4(
                    af[mi], bfr[ni], accf[mi][ni],
                    0, 0,                 // cbsz=fp8(e4m3), blgp=fp8(e4m3)
                    0, 0x7f7f7f7f,        // scale_a: every byte = 2^0
                    0, 0x7f7f7f7f);       // scale_b
    }

    // epilogue: exp(10*d) = exp2(d*10/ln2); skip pos diagonal (bx==by tiles only)
    const float LOG2E10 = 14.4269504088896341f;
    float part = 0.f;
    if (pos && bx == by) {
        #pragma unroll
        for (int mi = 0; mi < 2; ++mi)
            #pragma unroll
            for (int ni = 0; ni < 2; ++ni)
                #pragma unroll
                for (int r = 0; r < 16; ++r) {
                    // C/D 32x32: col=lane&31, row=(r&3)+8*(r>>2)+4*(lane>>5)
                    int rr = wm + mi * 32 + ((r & 3) + 8 * (r >> 2) + 4 * (lane >> 5));
                    int cc = wn + ni * 32 + (lane & 31);
                    if (rr != cc) part += exp2f(accf[mi][ni][r] * LOG2E10);
                }
    } else {
        #pragma unroll
        for (int mi = 0; mi < 2; ++mi)
            #pragma unroll
            for (int ni = 0; ni < 2; ++ni)
                #pragma unroll
                for (int r = 0; r < 16; ++r)
                    part += exp2f(accf[mi][ni][r] * LOG2E10);
    }

    #pragma unroll
    for (int off = 32; off >= 1; off >>= 1) part += __shfl_xor(part, off, 64);
    if (lane == 0) red[wave] = part;
    __syncthreads();
    if (tid == 0) {
        double s = (double)red[0] + (double)red[1] + (double)red[2] + (double)red[3];
        if (pos && bx > by) s *= 2.0;    // upper-tri pos block stands in for its mirror
        atomicAdd(&acc[pos ? 0 : 1], s);
        __threadfence();
        unsigned t = atomicAdd(cnt, 1u);
        if (t == NPART - 1) {   // last participating block finalizes
            double posS = __hip_atomic_load(&acc[0], __ATOMIC_RELAXED,
                                            __HIP_MEMORY_SCOPE_AGENT) + 8192.0 * exp(10.0);
            double negS = __hip_atomic_load(&acc[1], __ATOMIC_RELAXED,
                                            __HIP_MEMORY_SCOPE_AGENT);
            out[0] = (float)log1p(negS / posS);
        }
    }
}

extern "C" void kernel_launch(void* const* d_in, const int* in_sizes, int n_in,
                              void* d_out, int out_size, void* d_ws, size_t ws_size,
                              hipStream_t stream) {
    const float* zi = (const float*)d_in[0];
    const float* zj = (const float*)d_in[1];
    u8* nrm = (u8*)d_ws;                                      // [16384][512] fp8 = 8 MB
    double* acc = (double*)((char*)d_ws + (size_t)16384 * 512);
    unsigned* cnt = (unsigned*)(acc + 2);

    nrm_kernel<<<4096, 256, 0, stream>>>(zi, zj, nrm, acc, cnt);
    dim3 grid(128, 64);   // x: 16384/128 n-tiles, y: 8192/128 m-tiles
    gemm_exp_reduce<<<grid, 256, 0, stream>>>(nrm, nrm, acc, cnt, (float*)d_out);
}

// Round 8
// 167.815 us; speedup vs baseline: 1.9207x; 1.5952x over previous
//
#include <hip/hip_runtime.h>
#include <cstdint>
#include <cmath>

#define NROWS 8192
#define KDIM  512            // elements; also bytes/row in fp8

typedef int    i32x4  __attribute__((ext_vector_type(4)));
typedef int    i32x8  __attribute__((ext_vector_type(8)));
typedef float  f32x16 __attribute__((ext_vector_type(16)));
typedef unsigned char u8;

#define AS1(p) ((const __attribute__((address_space(1))) void*)(p))
#define AS3(p) ((__attribute__((address_space(3))) void*)(p))

// --- Kernel 1: row L2-normalize fp32 -> fp8 e4m3 (OCP, HW cvt), one wave/row.
// zi rows [0,8192), zj rows [8192,16384). Also zeroes accumulators.
__global__ __launch_bounds__(256) void nrm_kernel(const float* __restrict__ zi,
                                                  const float* __restrict__ zj,
                                                  u8* __restrict__ out,
                                                  double* __restrict__ acc) {
    if (blockIdx.x == 0 && threadIdx.x == 0) { acc[0] = 0.0; acc[1] = 0.0; }
    const int wave = threadIdx.x >> 6;
    const int lane = threadIdx.x & 63;
    const int row  = blockIdx.x * 4 + wave;            // 0..16383
    const float* src = (row < NROWS) ? zi + (size_t)row * KDIM
                                     : zj + (size_t)(row - NROWS) * KDIM;
    float4 a = ((const float4*)src)[lane];
    float4 b = ((const float4*)src)[lane + 64];
    float ss = a.x*a.x + a.y*a.y + a.z*a.z + a.w*a.w
             + b.x*b.x + b.y*b.y + b.z*b.z + b.w*b.w;
    #pragma unroll
    for (int off = 32; off >= 1; off >>= 1) ss += __shfl_xor(ss, off, 64);
    const float inv = 1.0f / fmaxf(sqrtf(ss), 1e-12f);
    int p0 = 0, p1 = 0;
    p0 = __builtin_amdgcn_cvt_pk_fp8_f32(a.x * inv, a.y * inv, p0, false);
    p0 = __builtin_amdgcn_cvt_pk_fp8_f32(a.z * inv, a.w * inv, p0, true);
    p1 = __builtin_amdgcn_cvt_pk_fp8_f32(b.x * inv, b.y * inv, p1, false);
    p1 = __builtin_amdgcn_cvt_pk_fp8_f32(b.z * inv, b.w * inv, p1, true);
    int* dst = (int*)(out + (size_t)row * KDIM);
    dst[lane]      = p0;
    dst[lane + 64] = p1;
}

// --- Kernel 2: fused MX-fp8 A*B^T -> exp(10*dot) -> global sum.
// EXACT R3-measured structure (113 µs; best known): 128x128 block, 4 waves 2x2,
// wave tile 64x64 = 2x2 frags of 32x32x64, LDS XOR-swizzle, 2-barrier K-loop,
// plain device-scope atomicAdd per block, NO __threadfence / NO ticket counter
// (R4-R6 post-mortem: the fence's L2 writeback-invalidate ran every ~34 ns
// device-wide and made every block ~2.5x slower; kernel-boundary ordering is
// sufficient for the separate finalize launch).
// R6's verified triangle skip kept: pos matrix zi*zi^T is symmetric -> lower-tri
// pos blocks (bx<by) exit; bx>by pos blocks count with weight 2 (bitwise exact).
// Pos diagonal skipped here, added exactly in finalize.
__global__ __launch_bounds__(256) void gemm_exp_reduce(const u8* __restrict__ A,
                                                       const u8* __restrict__ B,
                                                       double* __restrict__ acc) {
    const int bx = blockIdx.x, by = blockIdx.y;
    const bool pos = (bx < 64);
    if (pos && bx < by) return;   // lower-triangle pos block: mirror of (by,bx)

    __shared__ u8 lA[128 * 64];   // 8 KB = 4 operand-tile regions of 2048 B
    __shared__ u8 lB[128 * 64];   // 8 KB
    __shared__ float red[4];

    const int tid  = threadIdx.x;
    const int lane = tid & 63;
    const int wave = tid >> 6;
    const int m0   = by * 128;
    const int n0   = bx * 128;
    const int wm   = (wave >> 1) * 64;
    const int wn   = (wave & 1) * 64;

    f32x16 accf[2][2];
    #pragma unroll
    for (int i = 0; i < 2; ++i)
        #pragma unroll
        for (int j = 0; j < 2; ++j)
            #pragma unroll
            for (int r = 0; r < 16; ++r)
                accf[i][j][r] = 0.f;

    // staging (verified R2/R3): wave w stages rows w*32..+31 into region w*2048;
    // instr c writes LDS [w*2048 + c*1024 + lane*16]; lane's global source is
    // row = w*32 + c*16 + (lane>>2), 16B-chunk b = (lane&3) ^ ((lane>>3)&3).
    const int bsw = (lane & 3) ^ ((lane >> 3) & 3);
    const u8* gA0 = A + (size_t)(m0 + wave * 32 + (lane >> 2)) * KDIM + bsw * 16;
    const u8* gB0 = B + (size_t)(n0 + wave * 32 + (lane >> 2)) * KDIM + bsw * 16;
    u8* lAd = &lA[wave * 2048 + lane * 16];
    u8* lBd = &lB[wave * 2048 + lane * 16];

    // fragment read: lane holds row r=lane&31, k-half q=lane>>5 (chunks 2q,2q+1);
    // swizzled chunk position p = r*4 + ((2q) ^ ((r>>1)&3))
    const int r_  = lane & 31;
    const int q_  = lane >> 5;
    const int p16 = (r_ * 4 + ((2 * q_) ^ ((r_ >> 1) & 3))) * 16;
    const int aT0 = (wave >> 1) * 2;
    const int bT0 = (wave & 1) * 2;

    for (int k0 = 0; k0 < KDIM; k0 += 64) {
        __syncthreads();
        #pragma unroll
        for (int c = 0; c < 2; ++c) {
            __builtin_amdgcn_global_load_lds(AS1(gA0 + k0 + (size_t)c * 16 * KDIM),
                                             AS3(lAd + c * 1024), 16, 0, 0);
            __builtin_amdgcn_global_load_lds(AS1(gB0 + k0 + (size_t)c * 16 * KDIM),
                                             AS3(lBd + c * 1024), 16, 0, 0);
        }
        __syncthreads();

        i32x8 af[2], bfr[2];
        #pragma unroll
        for (int mi = 0; mi < 2; ++mi) {
            const int off = (aT0 + mi) * 2048 + p16;
            i32x4 lo = *(const i32x4*)&lA[off];
            i32x4 hi = *(const i32x4*)&lA[off ^ 16];
            af[mi] = (i32x8){lo[0], lo[1], lo[2], lo[3], hi[0], hi[1], hi[2], hi[3]};
        }
        #pragma unroll
        for (int ni = 0; ni < 2; ++ni) {
            const int off = (bT0 + ni) * 2048 + p16;
            i32x4 lo = *(const i32x4*)&lB[off];
            i32x4 hi = *(const i32x4*)&lB[off ^ 16];
            bfr[ni] = (i32x8){lo[0], lo[1], lo[2], lo[3], hi[0], hi[1], hi[2], hi[3]};
        }
        #pragma unroll
        for (int mi = 0; mi < 2; ++mi)
            #pragma unroll
            for (int ni = 0; ni < 2; ++ni)
                accf[mi][ni] = __builtin_amdgcn_mfma_scale_f32_32x32x64_f8f6f4(
                    af[mi], bfr[ni], accf[mi][ni],
                    0, 0,                 // cbsz=fp8(e4m3), blgp=fp8(e4m3)
                    0, 0x7f7f7f7f,        // scale_a: every byte = 2^0
                    0, 0x7f7f7f7f);       // scale_b
    }

    // epilogue: exp(10*d) = exp2(d*10/ln2); skip pos diagonal (bx==by tiles only)
    const float LOG2E10 = 14.4269504088896341f;
    float part = 0.f;
    if (pos && bx == by) {
        #pragma unroll
        for (int mi = 0; mi < 2; ++mi)
            #pragma unroll
            for (int ni = 0; ni < 2; ++ni)
                #pragma unroll
                for (int r = 0; r < 16; ++r) {
                    // C/D 32x32: col=lane&31, row=(r&3)+8*(r>>2)+4*(lane>>5)
                    int rr = wm + mi * 32 + ((r & 3) + 8 * (r >> 2) + 4 * (lane >> 5));
                    int cc = wn + ni * 32 + (lane & 31);
                    if (rr != cc) part += exp2f(accf[mi][ni][r] * LOG2E10);
                }
    } else {
        #pragma unroll
        for (int mi = 0; mi < 2; ++mi)
            #pragma unroll
            for (int ni = 0; ni < 2; ++ni)
                #pragma unroll
                for (int r = 0; r < 16; ++r)
                    part += exp2f(accf[mi][ni][r] * LOG2E10);
    }

    #pragma unroll
    for (int off = 32; off >= 1; off >>= 1) part += __shfl_xor(part, off, 64);
    if (lane == 0) red[wave] = part;
    __syncthreads();
    if (tid == 0) {
        double s = (double)red[0] + (double)red[1] + (double)red[2] + (double)red[3];
        if (pos && bx > by) s *= 2.0;    // upper-tri pos block stands in for its mirror
        atomicAdd(&acc[pos ? 0 : 1], s);
    }
}

// --- Kernel 3: loss = log1p(neg / pos), pos += exact diagonal 8192*e^10 ---
__global__ void finalize(const double* __restrict__ acc, float* __restrict__ out) {
    double pos = acc[0] + 8192.0 * exp(10.0);
    out[0] = (float)log1p(acc[1] / pos);
}

extern "C" void kernel_launch(void* const* d_in, const int* in_sizes, int n_in,
                              void* d_out, int out_size, void* d_ws, size_t ws_size,
                              hipStream_t stream) {
    const float* zi = (const float*)d_in[0];
    const float* zj = (const float*)d_in[1];
    u8* nrm = (u8*)d_ws;                                      // [16384][512] fp8 = 8 MB
    double* acc = (double*)((char*)d_ws + (size_t)16384 * 512);

    nrm_kernel<<<4096, 256, 0, stream>>>(zi, zj, nrm, acc);
    dim3 grid(128, 64);   // x: 16384/128 n-tiles, y: 8192/128 m-tiles
    gemm_exp_reduce<<<grid, 256, 0, stream>>>(nrm, nrm, acc);
    finalize<<<1, 1, 0, stream>>>(acc, (float*)d_out);
}